// Round 6
// baseline (292.395 us; speedup 1.0000x reference)
//
#include <hip/hip_runtime.h>

#define D 128
#define MARGIN 1.0f
#define ALFA 0.1f
#define KC 32          // gram chunk rows (main path)
#define GRAMB 1024     // gram blocks (main path)
#define RBLK 520       // reduce blocks fused into triplet launch (8 slices x 65)
#define TB 2048        // triplet blocks
#define GB 512         // fallback gram blocks

// ws layout (floats):
// [0] tsum | [256..16640) gram | [16640..16768) colsum | [16896..) partials | bf16 table
#define WS_TSUM   0
#define WS_GRAM   256
#define WS_COLSUM (WS_GRAM + D * D)
#define WS_ZERO   (WS_COLSUM + D)
#define WS_PART   16896
#define PART_STRIDE (D * D + D)                      // 16512 floats per gram-block partial
#define WS_TAB_F  (WS_PART + GRAMB * PART_STRIDE)    // float index of bf16 table start

typedef __attribute__((ext_vector_type(8)))  short bf16x8;
typedef __attribute__((ext_vector_type(8)))  unsigned short u16x8;
typedef __attribute__((ext_vector_type(16))) float f32x16;

__device__ __forceinline__ unsigned short f2bf(float f) {
    unsigned u = __float_as_uint(f);
    u += 0x7FFFu + ((u >> 16) & 1u);   // RNE
    return (unsigned short)(u >> 16);
}
__device__ __forceinline__ float bf2f(unsigned short u) {
    return __uint_as_float((unsigned)u << 16);
}

// ---------------------------------------------------------------------------
// Kernel A: Gram via bf16 MFMA (32x32x16) + bf16 table emission.
// GRAMB=1024 blocks x 512 thr -> 4 blocks/CU co-resident (LDS ~17 KB):
// staggered per-block barriers keep HBM busy (R5 showed 1.3 blocks/CU ->
// 33% duty cycle). KC=32 rows staged transposed bf16 in LDS, double-buffered,
// 4-slot XOR swizzle (write & read use the same involution).
// Gram is symmetric (G = X^T X) -> C/D transpose harmless.
// ---------------------------------------------------------------------------
__global__ __launch_bounds__(512, 4) void gram_mfma_write(const float* __restrict__ emb,
                                                          int rowsPerBlock,
                                                          float* __restrict__ ws,
                                                          unsigned short* __restrict__ tab) {
    __shared__ __align__(16) char lds[2][128 * 64];   // 2 x (128 d-rows x 64 B) = 16 KiB
    __shared__ float csred[D];

    const int tid = threadIdx.x;
    const int l   = tid & 63;
    const int w   = tid >> 6;
    const int r0  = blockIdx.x * rowsPerBlock;

    const int rT = w & 3;              // row tile 0..3
    const int c0 = (w >> 2) * 2;       // col tiles c0, c0+1

    f32x16 acc0 = {};
    f32x16 acc1 = {};
    float cs[4] = {0.f, 0.f, 0.f, 0.f};
    const int d0 = (tid & 31) * 4;     // dim group this thread stages
    const int ks = (tid >> 5) * 2;     // row pair within chunk (0,2,..,30)

    auto stage = [&](int cc, int b) {
        const int rowg = r0 + cc * KC + ks;
        const float* base = emb + (size_t)rowg * D + d0;
        float4 a  = *(const float4*)base;
        float4 bv = *(const float4*)(base + D);
        ushort4 ua, ub;
        unsigned short* pa = (unsigned short*)&ua;
        unsigned short* pb = (unsigned short*)&ub;
#pragma unroll
        for (int i = 0; i < 4; ++i) {
            float av = ((const float*)&a)[i];
            float bb = ((const float*)&bv)[i];
            cs[i] += av + bb;
            unsigned short ha = f2bf(av), hb = f2bf(bb);
            pa[i] = ha; pb[i] = hb;
            unsigned slotp = (unsigned)(ks >> 3) ^ ((unsigned)((d0 + i) >> 2) & 3u);
            unsigned off = (unsigned)(d0 + i) * 64u + slotp * 16u + (unsigned)((ks & 7) << 1);
            *(unsigned*)(&lds[b][off]) = (unsigned)ha | ((unsigned)hb << 16);
        }
        // bf16 table emission: 8B/lane, 256B contiguous per 32-lane row
        *(ushort4*)&tab[(size_t)rowg * D + d0]       = ua;
        *(ushort4*)&tab[(size_t)(rowg + 1) * D + d0] = ub;
    };

    auto frag = [&](int t, int kb, int b) -> bf16x8 {
        const int d = t * 32 + (l & 31);
        const int k = kb + (l >> 5) * 8;
        unsigned slotp = (unsigned)(k >> 3) ^ ((unsigned)(d >> 2) & 3u);
        return *(const bf16x8*)(&lds[b][(unsigned)d * 64u + slotp * 16u]);
    };

    const int nChunks = rowsPerBlock / KC;   // 256/32 = 8
    stage(0, 0);
    for (int cc = 0; cc < nChunks; ++cc) {
        const int b = cc & 1;
        __syncthreads();                       // buf b staged; buf b^1 free
        if (cc + 1 < nChunks) stage(cc + 1, b ^ 1);
#pragma unroll
        for (int kb = 0; kb < KC; kb += 16) {
            bf16x8 fr = frag(rT,     kb, b);
            bf16x8 f0 = frag(c0,     kb, b);
            bf16x8 f1 = frag(c0 + 1, kb, b);
            acc0 = __builtin_amdgcn_mfma_f32_32x32x16_bf16(fr, f0, acc0, 0, 0, 0);
            acc1 = __builtin_amdgcn_mfma_f32_32x32x16_bf16(fr, f1, acc1, 0, 0, 0);
        }
    }
    __syncthreads();

    if (tid < D) csred[tid] = 0.f;
    __syncthreads();
#pragma unroll
    for (int i = 0; i < 4; ++i) atomicAdd(&csred[d0 + i], cs[i]);
    __syncthreads();

    float* gram   = ws + WS_PART + (size_t)blockIdx.x * PART_STRIDE;
    float* colsum = gram + D * D;

    if (tid < D) colsum[tid] = csred[tid];

    // C/D layout (verified m74/m101): col = l&31, row = (reg&3)+8*(reg>>2)+4*(l>>5)
    const int row_hi = (l >> 5) * 4;
    const int col    = l & 31;
#pragma unroll
    for (int reg = 0; reg < 16; ++reg) {
        const int row32 = (reg & 3) + 8 * (reg >> 2) + row_hi;
        const int gr    = (rT * 32 + row32) * D;
        gram[gr + c0 * 32 + col]       = acc0[reg];
        gram[gr + (c0 + 1) * 32 + col] = acc1[reg];
    }
}

// ---------------------------------------------------------------------------
// Kernel B (block-specialized):
//   blocks [0, RBLK)      : sum gram partials into gram+colsum (8 slices x 65)
//   blocks [RBLK, +TB)    : triplet loss from bf16 table, 16-lane group per
//                           triplet, ushort8/lane, 6 triplets in flight.
// Reduce blocks dispatch first and overlap the triplet ramp.
// ---------------------------------------------------------------------------
__global__ __launch_bounds__(256) void triplet_red(const unsigned short* __restrict__ tab,
                                                   const int* __restrict__ trip,
                                                   int T,
                                                   float* __restrict__ ws) {
    __shared__ float red[16];
    const int tid = threadIdx.x;

    if (blockIdx.x < RBLK) {
        // ---- partial reduction ----
        const int idx   = (blockIdx.x % 65) * 256 + tid;
        const int slice = blockIdx.x / 65;
        if (idx >= PART_STRIDE) return;
        const int per = GRAMB / 8;            // 128 partials per slice
        const float* part = ws + WS_PART;
        float s = 0.f;
        const int p0 = slice * per;
#pragma unroll 8
        for (int p = 0; p < per; ++p)
            s += part[(size_t)(p0 + p) * PART_STRIDE + idx];
        if (idx < D * D) atomicAdd(&ws[WS_GRAM + idx], s);
        else             atomicAdd(&ws[WS_COLSUM + (idx - D * D)], s);
        return;
    }

    // ---- triplet loss ----
    const int li  = tid & 15;
    const int grp = ((blockIdx.x - RBLK) * 256 + tid) >> 4;
    const int NG  = (TB * 256) >> 4;

    float wsum = 0.f;

    for (int t0 = grp; t0 < T; t0 += 6 * NG) {
        u16x8 P[6], Q[6], R[6];
#pragma unroll
        for (int u = 0; u < 6; ++u) {
            const int t = t0 + u * NG;
            if (t < T) {
                const int i0 = trip[3 * t], i1 = trip[3 * t + 1], i2 = trip[3 * t + 2];
                P[u] = *(const u16x8*)&tab[(size_t)i0 * D + li * 8];
                Q[u] = *(const u16x8*)&tab[(size_t)i1 * D + li * 8];
                R[u] = *(const u16x8*)&tab[(size_t)i2 * D + li * 8];
            }
        }
#pragma unroll
        for (int u = 0; u < 6; ++u) {
            const int t = t0 + u * NG;
            if (t < T) {
                float s = 0.f;
#pragma unroll
                for (int e = 0; e < 8; ++e) {
                    float p  = bf2f(P[u][e]);
                    float dp = p - bf2f(Q[u][e]);
                    float dn = p - bf2f(R[u][e]);
                    s += dp * dp - dn * dn;
                }
#pragma unroll
                for (int off = 8; off; off >>= 1) s += __shfl_xor(s, off, 64);
                if (li == 0) wsum += fmaxf(s + MARGIN, 0.f);
            }
        }
    }

    if (li == 0) red[tid >> 4] = wsum;
    __syncthreads();
    if (tid == 0) {
        float b = 0.f;
#pragma unroll
        for (int i = 0; i < 16; ++i) b += red[i];
        atomicAdd(&ws[WS_TSUM], b);
    }
}

// ---------------------------------------------------------------------------
// Finalize: cov/corr^2 tril mean + combine.
// ---------------------------------------------------------------------------
__global__ __launch_bounds__(256) void finalize_kernel(const float* __restrict__ ws,
                                                       float* __restrict__ out,
                                                       int N, int T) {
    const float* gram   = ws + WS_GRAM;
    const float* colsum = ws + WS_COLSUM;

    __shared__ float V[D];
    __shared__ float red[256];

    const int tid = threadIdx.x;
    const float invN   = 1.0f / (float)N;
    const float invNm1 = 1.0f / (float)(N - 1);

    if (tid < D) {
        float m = colsum[tid] * invN;
        V[tid] = (gram[tid * D + tid] - (float)N * m * m) * invNm1;
    }
    __syncthreads();

    float local = 0.f;
    for (int idx = tid; idx < D * D; idx += 256) {
        int i = idx >> 7, j = idx & 127;
        if (j < i) {
            float mi  = colsum[i] * invN;
            float mj  = colsum[j] * invN;
            float cov = (gram[idx] - (float)N * mi * mj) * invNm1;
            local += cov * cov / (V[i] * V[j]);
        }
    }
    red[tid] = local;
    __syncthreads();
    for (int s = 128; s > 0; s >>= 1) {
        if (tid < s) red[tid] += red[tid + s];
        __syncthreads();
    }
    if (tid == 0) {
        float corr_mean = red[0] / ((float)D * (float)(D - 1) * 0.5f);
        out[0] = ws[WS_TSUM] / (float)T + ALFA * corr_mean;
    }
}

// ---------------------------------------------------------------------------
// Fallback (ws too small for partials+table): atomic gram + fp32 triplet,
// block-specialized (R4-proven path, KC=64, 8-slot swizzle).
// ---------------------------------------------------------------------------
__device__ __forceinline__ float d2diff(float4 p, float4 q, float4 r) {
    float ax = p.x - q.x, ay = p.y - q.y, az = p.z - q.z, aw = p.w - q.w;
    float bx = p.x - r.x, by = p.y - r.y, bz = p.z - r.z, bw = p.w - r.w;
    return (ax * ax + ay * ay + az * az + aw * aw)
         - (bx * bx + by * by + bz * bz + bw * bw);
}

__global__ __launch_bounds__(512, 4) void fused_fallback(const float* __restrict__ emb,
                                                         const int* __restrict__ trip,
                                                         int rowsPerBlock, int T,
                                                         float* __restrict__ ws) {
    __shared__ __align__(16) char lds[2][128 * 128];
    __shared__ float csred[D];
    const int tid = threadIdx.x;

    if (blockIdx.x < GB) {
        const int l = tid & 63, w = tid >> 6, r0 = blockIdx.x * rowsPerBlock;
        const int rT = w & 3, c0 = (w >> 2) * 2;
        f32x16 acc0 = {}, acc1 = {};
        float cs[4] = {0.f, 0.f, 0.f, 0.f};
        const int d0 = (tid & 31) * 4;

        auto stage = [&](int cc, int b) {
#pragma unroll
            for (int j = 0; j < 2; ++j) {
                const int k = j * 32 + (tid >> 5) * 2;
                const float* base = emb + (size_t)(r0 + cc * 64 + k) * D + d0;
                float4 a = *(const float4*)base;
                float4 bv = *(const float4*)(base + D);
#pragma unroll
                for (int i = 0; i < 4; ++i) {
                    float av = ((const float*)&a)[i], bb = ((const float*)&bv)[i];
                    cs[i] += av + bb;
                    unsigned slotp = (unsigned)(k >> 3) ^ (unsigned)((tid & 31) & 7);
                    unsigned off = (unsigned)(d0 + i) * 128u + slotp * 16u + (unsigned)((k & 7) << 1);
                    *(unsigned*)(&lds[b][off]) = (unsigned)f2bf(av) | ((unsigned)f2bf(bb) << 16);
                }
            }
        };
        auto frag = [&](int t, int kb, int b) -> bf16x8 {
            const int d = t * 32 + (l & 31);
            const int k = kb + (l >> 5) * 8;
            unsigned slotp = (unsigned)(k >> 3) ^ ((unsigned)(d >> 2) & 7u);
            return *(const bf16x8*)(&lds[b][(unsigned)d * 128u + slotp * 16u]);
        };
        const int nChunks = rowsPerBlock / 64;
        stage(0, 0);
        for (int cc = 0; cc < nChunks; ++cc) {
            const int b = cc & 1;
            __syncthreads();
            if (cc + 1 < nChunks) stage(cc + 1, b ^ 1);
#pragma unroll
            for (int kb = 0; kb < 64; kb += 16) {
                bf16x8 fr = frag(rT, kb, b);
                bf16x8 f0 = frag(c0, kb, b);
                bf16x8 f1 = frag(c0 + 1, kb, b);
                acc0 = __builtin_amdgcn_mfma_f32_32x32x16_bf16(fr, f0, acc0, 0, 0, 0);
                acc1 = __builtin_amdgcn_mfma_f32_32x32x16_bf16(fr, f1, acc1, 0, 0, 0);
            }
        }
        __syncthreads();
        if (tid < D) csred[tid] = 0.f;
        __syncthreads();
#pragma unroll
        for (int i = 0; i < 4; ++i) atomicAdd(&csred[d0 + i], cs[i]);
        __syncthreads();
        if (tid < D) atomicAdd(&ws[WS_COLSUM + tid], csred[tid]);
        const int row_hi = (l >> 5) * 4, col = l & 31;
#pragma unroll
        for (int reg = 0; reg < 16; ++reg) {
            const int row32 = (reg & 3) + 8 * (reg >> 2) + row_hi;
            const int gr = (rT * 32 + row32) * D;
            atomicAdd(&ws[WS_GRAM + gr + c0 * 32 + col], acc0[reg]);
            atomicAdd(&ws[WS_GRAM + gr + (c0 + 1) * 32 + col], acc1[reg]);
        }
    } else {
        const int li = tid & 31, hwl = tid >> 5;
        const int hw = (blockIdx.x - GB) * 16 + hwl;
        const int NH = 1024 * 16;
        float wsum = 0.f;
        for (int t0 = hw; t0 < T; t0 += 4 * NH) {
            float4 P[4], Q[4], R[4];
#pragma unroll
            for (int k = 0; k < 4; ++k) {
                const int t = t0 + k * NH;
                if (t < T) {
                    const int i0 = trip[3 * t], i1 = trip[3 * t + 1], i2 = trip[3 * t + 2];
                    P[k] = ((const float4*)(emb + (size_t)i0 * D))[li];
                    Q[k] = ((const float4*)(emb + (size_t)i1 * D))[li];
                    R[k] = ((const float4*)(emb + (size_t)i2 * D))[li];
                }
            }
#pragma unroll
            for (int k = 0; k < 4; ++k) {
                const int t = t0 + k * NH;
                if (t < T) {
                    float s = d2diff(P[k], Q[k], R[k]);
#pragma unroll
                    for (int off = 16; off; off >>= 1) s += __shfl_xor(s, off, 64);
                    if (li == 0) wsum += fmaxf(s + MARGIN, 0.f);
                }
            }
        }
        if (li == 0) csred[hwl] = wsum;
        __syncthreads();
        if (tid == 0) {
            float b = 0.f;
#pragma unroll
            for (int i = 0; i < 16; ++i) b += csred[i];
            atomicAdd(&ws[WS_TSUM], b);
        }
    }
}

extern "C" void kernel_launch(void* const* d_in, const int* in_sizes, int n_in,
                              void* d_out, int out_size, void* d_ws, size_t ws_size,
                              hipStream_t stream) {
    const float* emb  = (const float*)d_in[0];
    const int*   trip = (const int*)d_in[1];
    float*       out  = (float*)d_out;
    float*       ws   = (float*)d_ws;

    const int N = in_sizes[0] / D;   // 262144
    const int T = in_sizes[1] / 3;   // 262144

    hipMemsetAsync(d_ws, 0, WS_ZERO * sizeof(float), stream);

    const size_t needB = (size_t)WS_TAB_F * 4 + (size_t)N * D * 2;   // partials + bf16 table

    if (ws_size >= needB) {
        unsigned short* tab = (unsigned short*)(ws + WS_TAB_F);
        gram_mfma_write<<<GRAMB, 512, 0, stream>>>(emb, N / GRAMB, ws, tab);
        triplet_red<<<RBLK + TB, 256, 0, stream>>>(tab, trip, T, ws);
    } else {
        fused_fallback<<<GB + 1024, 512, 0, stream>>>(emb, trip, N / GB, T, ws);
    }

    finalize_kernel<<<1, 256, 0, stream>>>(ws, out, N, T);
}

// Round 8
// 279.623 us; speedup vs baseline: 1.0457x; 1.0457x over previous
//
#include <hip/hip_runtime.h>

#define D 128
#define MARGIN 1.0f
#define ALFA 0.1f
#define KC 64          // gram chunk rows
#define GRAMB 512      // gram blocks
#define RBLK 520       // reduce blocks fused into triplet launch (8 slices x 65)
#define TB 2048        // triplet blocks
#define GB 512         // fallback gram blocks

// ws layout (floats):
// [0] tsum | [256..16640) gram | [16640..16768) colsum | [16896..) partials | bf16 table
#define WS_TSUM   0
#define WS_GRAM   256
#define WS_COLSUM (WS_GRAM + D * D)
#define WS_ZERO   (WS_COLSUM + D)
#define WS_PART   16896
#define PART_STRIDE (D * D + D)                      // 16512 floats per gram-block partial
#define WS_TAB_F  (WS_PART + GRAMB * PART_STRIDE)    // float index of bf16 table start

typedef __attribute__((ext_vector_type(8)))  short bf16x8;
typedef __attribute__((ext_vector_type(8)))  unsigned short u16x8;
typedef __attribute__((ext_vector_type(16))) float f32x16;

__device__ __forceinline__ unsigned short f2bf(float f) {
    unsigned u = __float_as_uint(f);
    u += 0x7FFFu + ((u >> 16) & 1u);   // RNE
    return (unsigned short)(u >> 16);
}
__device__ __forceinline__ float bf2f(unsigned short u) {
    return __uint_as_float((unsigned)u << 16);
}

// Light barrier: order LDS producer->consumer across the block WITHOUT
// draining vmcnt — global table-stores and prefetch loads stay in flight.
// (T4: __syncthreads' vmcnt(0) drain was the R5/R6 stall suspect.)
__device__ __forceinline__ void lds_barrier() {
    asm volatile("s_waitcnt lgkmcnt(0)" ::: "memory");
    __builtin_amdgcn_s_barrier();
}

// ---------------------------------------------------------------------------
// Kernel A: Gram via bf16 MFMA (32x32x16) + bf16 table emission.
// GRAMB=512 blocks x 512 thr. KC=64 rows staged transposed bf16 in LDS,
// double-buffered, 8-slot XOR swizzle (write & read same involution,
// R4-verified). Hot loop uses lds_barrier(): stores/loads uncounted ->
// no per-chunk store-ack serialization.
// Gram is symmetric (G = X^T X) -> C/D transpose harmless.
// ---------------------------------------------------------------------------
__global__ __launch_bounds__(512, 4) void gram_mfma_write(const float* __restrict__ emb,
                                                          int rowsPerBlock,
                                                          float* __restrict__ ws,
                                                          unsigned short* __restrict__ tab) {
    __shared__ __align__(16) char lds[2][128 * 128];   // 2 x (128 d-rows x 128 B) = 32 KiB
    __shared__ float csred[D];

    const int tid = threadIdx.x;
    const int l   = tid & 63;
    const int w   = tid >> 6;
    const int r0  = blockIdx.x * rowsPerBlock;

    const int rT = w & 3;              // row tile 0..3
    const int c0 = (w >> 2) * 2;       // col tiles c0, c0+1

    f32x16 acc0 = {};
    f32x16 acc1 = {};
    float cs[4] = {0.f, 0.f, 0.f, 0.f};
    const int d0 = (tid & 31) * 4;     // dim group this thread stages

    auto stage = [&](int cc, int b) {
#pragma unroll
        for (int j = 0; j < 2; ++j) {
            const int k = j * 32 + (tid >> 5) * 2;   // even row in chunk
            const int rowg = r0 + cc * KC + k;
            const float* base = emb + (size_t)rowg * D + d0;
            float4 a  = *(const float4*)base;
            float4 bv = *(const float4*)(base + D);
            ushort4 ua, ub;
            unsigned short* pa = (unsigned short*)&ua;
            unsigned short* pb = (unsigned short*)&ub;
#pragma unroll
            for (int i = 0; i < 4; ++i) {
                float av = ((const float*)&a)[i];
                float bb = ((const float*)&bv)[i];
                cs[i] += av + bb;
                unsigned short ha = f2bf(av), hb = f2bf(bb);
                pa[i] = ha; pb[i] = hb;
                unsigned slotp = (unsigned)(k >> 3) ^ (unsigned)((tid & 31) & 7); // == (d>>2)&7
                unsigned off = (unsigned)(d0 + i) * 128u + slotp * 16u + (unsigned)((k & 7) << 1);
                *(unsigned*)(&lds[b][off]) = (unsigned)ha | ((unsigned)hb << 16);
            }
            // bf16 table emission: 8B/lane, 256B contiguous per 32-lane group
            *(ushort4*)&tab[(size_t)rowg * D + d0]       = ua;
            *(ushort4*)&tab[(size_t)(rowg + 1) * D + d0] = ub;
        }
    };

    auto frag = [&](int t, int kb, int b) -> bf16x8 {
        const int d = t * 32 + (l & 31);
        const int k = kb + (l >> 5) * 8;
        unsigned slotp = (unsigned)(k >> 3) ^ ((unsigned)(d >> 2) & 7u);
        return *(const bf16x8*)(&lds[b][(unsigned)d * 128u + slotp * 16u]);
    };

    const int nChunks = rowsPerBlock / KC;   // 512/64 = 8
    stage(0, 0);
    for (int cc = 0; cc < nChunks; ++cc) {
        const int b = cc & 1;
        lds_barrier();                         // buf b staged; buf b^1 free
        if (cc + 1 < nChunks) stage(cc + 1, b ^ 1);
#pragma unroll
        for (int kb = 0; kb < KC; kb += 16) {
            bf16x8 fr = frag(rT,     kb, b);
            bf16x8 f0 = frag(c0,     kb, b);
            bf16x8 f1 = frag(c0 + 1, kb, b);
            acc0 = __builtin_amdgcn_mfma_f32_32x32x16_bf16(fr, f0, acc0, 0, 0, 0);
            acc1 = __builtin_amdgcn_mfma_f32_32x32x16_bf16(fr, f1, acc1, 0, 0, 0);
        }
    }
    __syncthreads();

    if (tid < D) csred[tid] = 0.f;
    __syncthreads();
#pragma unroll
    for (int i = 0; i < 4; ++i) atomicAdd(&csred[d0 + i], cs[i]);
    __syncthreads();

    float* gram   = ws + WS_PART + (size_t)blockIdx.x * PART_STRIDE;
    float* colsum = gram + D * D;

    if (tid < D) colsum[tid] = csred[tid];

    // C/D layout (verified m74/m101): col = l&31, row = (reg&3)+8*(reg>>2)+4*(l>>5)
    const int row_hi = (l >> 5) * 4;
    const int col    = l & 31;
#pragma unroll
    for (int reg = 0; reg < 16; ++reg) {
        const int row32 = (reg & 3) + 8 * (reg >> 2) + row_hi;
        const int gr    = (rT * 32 + row32) * D;
        gram[gr + c0 * 32 + col]       = acc0[reg];
        gram[gr + (c0 + 1) * 32 + col] = acc1[reg];
    }
}

// ---------------------------------------------------------------------------
// Kernel B (block-specialized):
//   blocks [0, RBLK)   : sum gram partials into gram+colsum (8 slices x 65)
//   blocks [RBLK, +TB) : triplet loss from bf16 table, 16-lane group per
//                        triplet, ushort8/lane, 6 triplets in flight.
// ---------------------------------------------------------------------------
__global__ __launch_bounds__(256) void triplet_red(const unsigned short* __restrict__ tab,
                                                   const int* __restrict__ trip,
                                                   int T,
                                                   float* __restrict__ ws) {
    __shared__ float red[16];
    const int tid = threadIdx.x;

    if (blockIdx.x < RBLK) {
        const int idx   = (blockIdx.x % 65) * 256 + tid;
        const int slice = blockIdx.x / 65;
        if (idx >= PART_STRIDE) return;
        const int per = GRAMB / 8;            // 64 partials per slice
        const float* part = ws + WS_PART;
        float s = 0.f;
        const int p0 = slice * per;
#pragma unroll 8
        for (int p = 0; p < per; ++p)
            s += part[(size_t)(p0 + p) * PART_STRIDE + idx];
        if (idx < D * D) atomicAdd(&ws[WS_GRAM + idx], s);
        else             atomicAdd(&ws[WS_COLSUM + (idx - D * D)], s);
        return;
    }

    const int li  = tid & 15;
    const int grp = ((blockIdx.x - RBLK) * 256 + tid) >> 4;
    const int NG  = (TB * 256) >> 4;

    float wsum = 0.f;

    for (int t0 = grp; t0 < T; t0 += 6 * NG) {
        u16x8 P[6], Q[6], R[6];
#pragma unroll
        for (int u = 0; u < 6; ++u) {
            const int t = t0 + u * NG;
            if (t < T) {
                const int i0 = trip[3 * t], i1 = trip[3 * t + 1], i2 = trip[3 * t + 2];
                P[u] = *(const u16x8*)&tab[(size_t)i0 * D + li * 8];
                Q[u] = *(const u16x8*)&tab[(size_t)i1 * D + li * 8];
                R[u] = *(const u16x8*)&tab[(size_t)i2 * D + li * 8];
            }
        }
#pragma unroll
        for (int u = 0; u < 6; ++u) {
            const int t = t0 + u * NG;
            if (t < T) {
                float s = 0.f;
#pragma unroll
                for (int e = 0; e < 8; ++e) {
                    float p  = bf2f(P[u][e]);
                    float dp = p - bf2f(Q[u][e]);
                    float dn = p - bf2f(R[u][e]);
                    s += dp * dp - dn * dn;
                }
#pragma unroll
                for (int off = 8; off; off >>= 1) s += __shfl_xor(s, off, 64);
                if (li == 0) wsum += fmaxf(s + MARGIN, 0.f);
            }
        }
    }

    if (li == 0) red[tid >> 4] = wsum;
    __syncthreads();
    if (tid == 0) {
        float b = 0.f;
#pragma unroll
        for (int i = 0; i < 16; ++i) b += red[i];
        atomicAdd(&ws[WS_TSUM], b);
    }
}

// ---------------------------------------------------------------------------
// Finalize: cov/corr^2 tril mean + combine.
// ---------------------------------------------------------------------------
__global__ __launch_bounds__(256) void finalize_kernel(const float* __restrict__ ws,
                                                       float* __restrict__ out,
                                                       int N, int T) {
    const float* gram   = ws + WS_GRAM;
    const float* colsum = ws + WS_COLSUM;

    __shared__ float V[D];
    __shared__ float red[256];

    const int tid = threadIdx.x;
    const float invN   = 1.0f / (float)N;
    const float invNm1 = 1.0f / (float)(N - 1);

    if (tid < D) {
        float m = colsum[tid] * invN;
        V[tid] = (gram[tid * D + tid] - (float)N * m * m) * invNm1;
    }
    __syncthreads();

    float local = 0.f;
    for (int idx = tid; idx < D * D; idx += 256) {
        int i = idx >> 7, j = idx & 127;
        if (j < i) {
            float mi  = colsum[i] * invN;
            float mj  = colsum[j] * invN;
            float cov = (gram[idx] - (float)N * mi * mj) * invNm1;
            local += cov * cov / (V[i] * V[j]);
        }
    }
    red[tid] = local;
    __syncthreads();
    for (int s = 128; s > 0; s >>= 1) {
        if (tid < s) red[tid] += red[tid + s];
        __syncthreads();
    }
    if (tid == 0) {
        float corr_mean = red[0] / ((float)D * (float)(D - 1) * 0.5f);
        out[0] = ws[WS_TSUM] / (float)T + ALFA * corr_mean;
    }
}

// ---------------------------------------------------------------------------
// Fallback (ws too small for partials+table): atomic gram + fp32 triplet,
// block-specialized (R4-proven path, KC=64, 8-slot swizzle).
// ---------------------------------------------------------------------------
__device__ __forceinline__ float d2diff(float4 p, float4 q, float4 r) {
    float ax = p.x - q.x, ay = p.y - q.y, az = p.z - q.z, aw = p.w - q.w;
    float bx = p.x - r.x, by = p.y - r.y, bz = p.z - r.z, bw = p.w - r.w;
    return (ax * ax + ay * ay + az * az + aw * aw)
         - (bx * bx + by * by + bz * bz + bw * bw);
}

__global__ __launch_bounds__(512, 4) void fused_fallback(const float* __restrict__ emb,
                                                         const int* __restrict__ trip,
                                                         int rowsPerBlock, int T,
                                                         float* __restrict__ ws) {
    __shared__ __align__(16) char lds[2][128 * 128];
    __shared__ float csred[D];
    const int tid = threadIdx.x;

    if (blockIdx.x < GB) {
        const int l = tid & 63, w = tid >> 6, r0 = blockIdx.x * rowsPerBlock;
        const int rT = w & 3, c0 = (w >> 2) * 2;
        f32x16 acc0 = {}, acc1 = {};
        float cs[4] = {0.f, 0.f, 0.f, 0.f};
        const int d0 = (tid & 31) * 4;

        auto stage = [&](int cc, int b) {
#pragma unroll
            for (int j = 0; j < 2; ++j) {
                const int k = j * 32 + (tid >> 5) * 2;
                const float* base = emb + (size_t)(r0 + cc * 64 + k) * D + d0;
                float4 a = *(const float4*)base;
                float4 bv = *(const float4*)(base + D);
#pragma unroll
                for (int i = 0; i < 4; ++i) {
                    float av = ((const float*)&a)[i], bb = ((const float*)&bv)[i];
                    cs[i] += av + bb;
                    unsigned slotp = (unsigned)(k >> 3) ^ (unsigned)((tid & 31) & 7);
                    unsigned off = (unsigned)(d0 + i) * 128u + slotp * 16u + (unsigned)((k & 7) << 1);
                    *(unsigned*)(&lds[b][off]) = (unsigned)f2bf(av) | ((unsigned)f2bf(bb) << 16);
                }
            }
        };
        auto frag = [&](int t, int kb, int b) -> bf16x8 {
            const int d = t * 32 + (l & 31);
            const int k = kb + (l >> 5) * 8;
            unsigned slotp = (unsigned)(k >> 3) ^ ((unsigned)(d >> 2) & 7u);
            return *(const bf16x8*)(&lds[b][(unsigned)d * 128u + slotp * 16u]);
        };
        const int nChunks = rowsPerBlock / 64;
        stage(0, 0);
        for (int cc = 0; cc < nChunks; ++cc) {
            const int b = cc & 1;
            __syncthreads();
            if (cc + 1 < nChunks) stage(cc + 1, b ^ 1);
#pragma unroll
            for (int kb = 0; kb < 64; kb += 16) {
                bf16x8 fr = frag(rT, kb, b);
                bf16x8 f0 = frag(c0, kb, b);
                bf16x8 f1 = frag(c0 + 1, kb, b);
                acc0 = __builtin_amdgcn_mfma_f32_32x32x16_bf16(fr, f0, acc0, 0, 0, 0);
                acc1 = __builtin_amdgcn_mfma_f32_32x32x16_bf16(fr, f1, acc1, 0, 0, 0);
            }
        }
        __syncthreads();
        if (tid < D) csred[tid] = 0.f;
        __syncthreads();
#pragma unroll
        for (int i = 0; i < 4; ++i) atomicAdd(&csred[d0 + i], cs[i]);
        __syncthreads();
        if (tid < D) atomicAdd(&ws[WS_COLSUM + tid], csred[tid]);
        const int row_hi = (l >> 5) * 4, col = l & 31;
#pragma unroll
        for (int reg = 0; reg < 16; ++reg) {
            const int row32 = (reg & 3) + 8 * (reg >> 2) + row_hi;
            const int gr = (rT * 32 + row32) * D;
            atomicAdd(&ws[WS_GRAM + gr + c0 * 32 + col], acc0[reg]);
            atomicAdd(&ws[WS_GRAM + gr + (c0 + 1) * 32 + col], acc1[reg]);
        }
    } else {
        const int li = tid & 31, hwl = tid >> 5;
        const int hw = (blockIdx.x - GB) * 16 + hwl;
        const int NH = 1024 * 16;
        float wsum = 0.f;
        for (int t0 = hw; t0 < T; t0 += 4 * NH) {
            float4 P[4], Q[4], R[4];
#pragma unroll
            for (int k = 0; k < 4; ++k) {
                const int t = t0 + k * NH;
                if (t < T) {
                    const int i0 = trip[3 * t], i1 = trip[3 * t + 1], i2 = trip[3 * t + 2];
                    P[k] = ((const float4*)(emb + (size_t)i0 * D))[li];
                    Q[k] = ((const float4*)(emb + (size_t)i1 * D))[li];
                    R[k] = ((const float4*)(emb + (size_t)i2 * D))[li];
                }
            }
#pragma unroll
            for (int k = 0; k < 4; ++k) {
                const int t = t0 + k * NH;
                if (t < T) {
                    float s = d2diff(P[k], Q[k], R[k]);
#pragma unroll
                    for (int off = 16; off; off >>= 1) s += __shfl_xor(s, off, 64);
                    if (li == 0) wsum += fmaxf(s + MARGIN, 0.f);
                }
            }
        }
        if (li == 0) csred[hwl] = wsum;
        __syncthreads();
        if (tid == 0) {
            float b = 0.f;
#pragma unroll
            for (int i = 0; i < 16; ++i) b += csred[i];
            atomicAdd(&ws[WS_TSUM], b);
        }
    }
}

extern "C" void kernel_launch(void* const* d_in, const int* in_sizes, int n_in,
                              void* d_out, int out_size, void* d_ws, size_t ws_size,
                              hipStream_t stream) {
    const float* emb  = (const float*)d_in[0];
    const int*   trip = (const int*)d_in[1];
    float*       out  = (float*)d_out;
    float*       ws   = (float*)d_ws;

    const int N = in_sizes[0] / D;   // 262144
    const int T = in_sizes[1] / 3;   // 262144

    hipMemsetAsync(d_ws, 0, WS_ZERO * sizeof(float), stream);

    const size_t needB = (size_t)WS_TAB_F * 4 + (size_t)N * D * 2;   // partials + bf16 table

    if (ws_size >= needB) {
        unsigned short* tab = (unsigned short*)(ws + WS_TAB_F);
        gram_mfma_write<<<GRAMB, 512, 0, stream>>>(emb, N / GRAMB, ws, tab);
        triplet_red<<<RBLK + TB, 256, 0, stream>>>(tab, trip, T, ws);
    } else {
        fused_fallback<<<GB + 1024, 512, 0, stream>>>(emb, trip, N / GB, T, ws);
    }

    finalize_kernel<<<1, 256, 0, stream>>>(ws, out, N, T);
}

// Round 9
// 272.823 us; speedup vs baseline: 1.0717x; 1.0249x over previous
//
#include <hip/hip_runtime.h>

#define D 128
#define MARGIN 1.0f
#define ALFA 0.1f
#define KC 64          // gram chunk rows
#define CVB 1024       // convert blocks
#define G2 256         // gram blocks (main path)
#define TB 1024        // triplet blocks in fused launch
#define GB 512         // fallback gram blocks

// ws layout (floats):
// [0] tsum | [256..16640) gram | [16640..16768) colsum | [16896..) partials | bf16 table
#define WS_TSUM   0
#define WS_GRAM   256
#define WS_COLSUM (WS_GRAM + D * D)
#define WS_ZERO   (WS_COLSUM + D)
#define WS_PART   16896
#define PSTRIDE   (D * D)                       // 16384 floats per gram partial (main path)
#define WS_TAB_F  (WS_PART + G2 * PSTRIDE)      // float index of bf16 table start

typedef __attribute__((ext_vector_type(8)))  short bf16x8;
typedef __attribute__((ext_vector_type(8)))  unsigned short u16x8;
typedef __attribute__((ext_vector_type(16))) float f32x16;

__device__ __forceinline__ unsigned short f2bf(float f) {
    unsigned u = __float_as_uint(f);
    u += 0x7FFFu + ((u >> 16) & 1u);   // RNE
    return (unsigned short)(u >> 16);
}
__device__ __forceinline__ float bf2f(unsigned short u) {
    return __uint_as_float((unsigned)u << 16);
}

// Light barrier: LDS producer->consumer ordering without draining vmcnt
// (R8-verified: gram left the top-5 after switching to this).
__device__ __forceinline__ void lds_barrier() {
    asm volatile("s_waitcnt lgkmcnt(0)" ::: "memory");
    __builtin_amdgcn_s_barrier();
}

// ---------------------------------------------------------------------------
// Kernel 0: streaming fp32 -> bf16 table convert + exact colsums.
// Pure BW-bound: 134 MB read + 67 MB write, no barriers in the hot loop.
// Lane layout: 32 lanes cover one 512B fp32 row (float4 each); 16 row-groups.
// ---------------------------------------------------------------------------
__global__ __launch_bounds__(512) void convert_kernel(const float* __restrict__ emb,
                                                      int rowsPerBlock,
                                                      float* __restrict__ ws,
                                                      unsigned short* __restrict__ tab) {
    __shared__ float csred[D];
    const int tid = threadIdx.x;
    const int cq  = tid & 31;          // column quad: dims 4cq..4cq+3
    const int rg  = tid >> 5;          // 0..15
    const int r0  = blockIdx.x * rowsPerBlock;

    float cs0 = 0.f, cs1 = 0.f, cs2 = 0.f, cs3 = 0.f;

#pragma unroll 4
    for (int r = rg; r < rowsPerBlock; r += 16) {
        const float4 v = *(const float4*)(emb + (size_t)(r0 + r) * D + cq * 4);
        cs0 += v.x; cs1 += v.y; cs2 += v.z; cs3 += v.w;
        ushort4 u;
        u.x = f2bf(v.x); u.y = f2bf(v.y); u.z = f2bf(v.z); u.w = f2bf(v.w);
        *(ushort4*)&tab[(size_t)(r0 + r) * D + cq * 4] = u;
    }

    if (tid < D) csred[tid] = 0.f;
    __syncthreads();
    atomicAdd(&csred[cq * 4 + 0], cs0);
    atomicAdd(&csred[cq * 4 + 1], cs1);
    atomicAdd(&csred[cq * 4 + 2], cs2);
    atomicAdd(&csred[cq * 4 + 3], cs3);
    __syncthreads();
    if (tid < D) atomicAdd(&ws[WS_COLSUM + tid], csred[tid]);
}

// ---------------------------------------------------------------------------
// Kernel 1 (fused, block-specialized):
//   blocks [0, G2)     : Gram from the L3-hot bf16 table (32x32x16 MFMA,
//                        KC=64 dbuf LDS, 8-slot XOR swizzle, lds_barrier).
//   blocks [G2, G2+TB) : triplet loss from the bf16 table, 16-lane groups,
//                        ushort8/lane, 4 triplets in flight.
// Both populations read the same 67 MB L3-resident table -> co-schedule.
// Gram is symmetric (G = X^T X) -> C/D transpose harmless.
// ---------------------------------------------------------------------------
__global__ __launch_bounds__(512, 4) void gram_trip(const unsigned short* __restrict__ tab,
                                                    const int* __restrict__ trip,
                                                    int T, int rowsPerBlock,
                                                    float* __restrict__ ws) {
    __shared__ __align__(16) char lds[2][128 * 128];   // 32 KiB (gram only)
    __shared__ float red[32];

    const int tid = threadIdx.x;

    if (blockIdx.x < G2) {
        // ================= GRAM PATH =================
        const int l  = tid & 63;
        const int w  = tid >> 6;
        const int r0 = blockIdx.x * rowsPerBlock;

        const int rT = w & 3;              // row tile 0..3
        const int c0 = (w >> 2) * 2;       // col tiles c0, c0+1

        f32x16 acc0 = {};
        f32x16 acc1 = {};

        const int k0 = (tid >> 4) * 2;     // even row in chunk (0..62)
        const int dg = (tid & 15) * 8;     // dim group (8 dims)

        auto stage = [&](int cc, int b) {
            const int rowg = r0 + cc * KC + k0;
            u16x8 A = *(const u16x8*)&tab[(size_t)rowg * D + dg];
            u16x8 B = *(const u16x8*)&tab[(size_t)(rowg + 1) * D + dg];
#pragma unroll
            for (int i = 0; i < 8; ++i) {
                const int d = dg + i;
                unsigned slotp = (unsigned)(k0 >> 3) ^ ((unsigned)(d >> 2) & 7u);
                unsigned off = (unsigned)d * 128u + slotp * 16u + (unsigned)((k0 & 7) << 1);
                *(unsigned*)(&lds[b][off]) =
                    (unsigned)(unsigned short)A[i] | ((unsigned)(unsigned short)B[i] << 16);
            }
        };

        auto frag = [&](int t, int kb, int b) -> bf16x8 {
            const int d = t * 32 + (l & 31);
            const int k = kb + (l >> 5) * 8;
            unsigned slotp = (unsigned)(k >> 3) ^ ((unsigned)(d >> 2) & 7u);
            return *(const bf16x8*)(&lds[b][(unsigned)d * 128u + slotp * 16u]);
        };

        const int nChunks = rowsPerBlock / KC;   // 1024/64 = 16
        stage(0, 0);
        for (int cc = 0; cc < nChunks; ++cc) {
            const int b = cc & 1;
            lds_barrier();                       // buf b staged; buf b^1 free
            if (cc + 1 < nChunks) stage(cc + 1, b ^ 1);
#pragma unroll
            for (int kb = 0; kb < KC; kb += 16) {
                bf16x8 fr = frag(rT,     kb, b);
                bf16x8 f0 = frag(c0,     kb, b);
                bf16x8 f1 = frag(c0 + 1, kb, b);
                acc0 = __builtin_amdgcn_mfma_f32_32x32x16_bf16(fr, f0, acc0, 0, 0, 0);
                acc1 = __builtin_amdgcn_mfma_f32_32x32x16_bf16(fr, f1, acc1, 0, 0, 0);
            }
        }
        __syncthreads();

        float* gram = ws + WS_PART + (size_t)blockIdx.x * PSTRIDE;

        // C/D layout (verified m74/m101): col = l&31, row = (reg&3)+8*(reg>>2)+4*(l>>5)
        const int row_hi = (l >> 5) * 4;
        const int col    = l & 31;
#pragma unroll
        for (int reg = 0; reg < 16; ++reg) {
            const int row32 = (reg & 3) + 8 * (reg >> 2) + row_hi;
            const int gr    = (rT * 32 + row32) * D;
            gram[gr + c0 * 32 + col]       = acc0[reg];
            gram[gr + (c0 + 1) * 32 + col] = acc1[reg];
        }
    } else {
        // ================= TRIPLET PATH =================
        const int li  = tid & 15;
        const int grp = (blockIdx.x - G2) * 32 + (tid >> 4);
        const int NG  = TB * 32;

        float wsum = 0.f;

        for (int t0 = grp; t0 < T; t0 += 4 * NG) {
            u16x8 P[4], Q[4], R[4];
#pragma unroll
            for (int u = 0; u < 4; ++u) {
                const int t = t0 + u * NG;
                if (t < T) {
                    const int i0 = trip[3 * t], i1 = trip[3 * t + 1], i2 = trip[3 * t + 2];
                    P[u] = *(const u16x8*)&tab[(size_t)i0 * D + li * 8];
                    Q[u] = *(const u16x8*)&tab[(size_t)i1 * D + li * 8];
                    R[u] = *(const u16x8*)&tab[(size_t)i2 * D + li * 8];
                }
            }
#pragma unroll
            for (int u = 0; u < 4; ++u) {
                const int t = t0 + u * NG;
                if (t < T) {
                    float s = 0.f;
#pragma unroll
                    for (int e = 0; e < 8; ++e) {
                        float p  = bf2f(P[u][e]);
                        float dp = p - bf2f(Q[u][e]);
                        float dn = p - bf2f(R[u][e]);
                        s += dp * dp - dn * dn;
                    }
#pragma unroll
                    for (int off = 8; off; off >>= 1) s += __shfl_xor(s, off, 64);
                    if (li == 0) wsum += fmaxf(s + MARGIN, 0.f);
                }
            }
        }

        if (li == 0) red[tid >> 4] = wsum;
        __syncthreads();
        if (tid == 0) {
            float b = 0.f;
#pragma unroll
            for (int i = 0; i < 32; ++i) b += red[i];
            atomicAdd(&ws[WS_TSUM], b);
        }
    }
}

// ---------------------------------------------------------------------------
// Kernel 2: sum G2 block-partials into gram (atomicAdd onto zeroed region).
// 256 blocks x 512 thr: 32 idx-blocks x 8 slices; 16384 = 32*512 exact.
// ---------------------------------------------------------------------------
__global__ __launch_bounds__(512) void reduce_partials(float* __restrict__ ws) {
    const int idx   = (blockIdx.x & 31) * 512 + threadIdx.x;
    const int slice = blockIdx.x >> 5;
    const int per   = G2 / 8;               // 32
    const float* part = ws + WS_PART;
    float s = 0.f;
    const int p0 = slice * per;
#pragma unroll 8
    for (int p = 0; p < per; ++p)
        s += part[(size_t)(p0 + p) * PSTRIDE + idx];
    atomicAdd(&ws[WS_GRAM + idx], s);
}

// ---------------------------------------------------------------------------
// Finalize: cov/corr^2 tril mean + combine.
// ---------------------------------------------------------------------------
__global__ __launch_bounds__(256) void finalize_kernel(const float* __restrict__ ws,
                                                       float* __restrict__ out,
                                                       int N, int T) {
    const float* gram   = ws + WS_GRAM;
    const float* colsum = ws + WS_COLSUM;

    __shared__ float V[D];
    __shared__ float red[256];

    const int tid = threadIdx.x;
    const float invN   = 1.0f / (float)N;
    const float invNm1 = 1.0f / (float)(N - 1);

    if (tid < D) {
        float m = colsum[tid] * invN;
        V[tid] = (gram[tid * D + tid] - (float)N * m * m) * invNm1;
    }
    __syncthreads();

    float local = 0.f;
    for (int idx = tid; idx < D * D; idx += 256) {
        int i = idx >> 7, j = idx & 127;
        if (j < i) {
            float mi  = colsum[i] * invN;
            float mj  = colsum[j] * invN;
            float cov = (gram[idx] - (float)N * mi * mj) * invNm1;
            local += cov * cov / (V[i] * V[j]);
        }
    }
    red[tid] = local;
    __syncthreads();
    for (int s = 128; s > 0; s >>= 1) {
        if (tid < s) red[tid] += red[tid + s];
        __syncthreads();
    }
    if (tid == 0) {
        float corr_mean = red[0] / ((float)D * (float)(D - 1) * 0.5f);
        out[0] = ws[WS_TSUM] / (float)T + ALFA * corr_mean;
    }
}

// ---------------------------------------------------------------------------
// Fallback (ws too small for partials+table): atomic gram + fp32 triplet,
// block-specialized (R4-proven path).
// ---------------------------------------------------------------------------
__device__ __forceinline__ float d2diff(float4 p, float4 q, float4 r) {
    float ax = p.x - q.x, ay = p.y - q.y, az = p.z - q.z, aw = p.w - q.w;
    float bx = p.x - r.x, by = p.y - r.y, bz = p.z - r.z, bw = p.w - r.w;
    return (ax * ax + ay * ay + az * az + aw * aw)
         - (bx * bx + by * by + bz * bz + bw * bw);
}

__global__ __launch_bounds__(512, 4) void fused_fallback(const float* __restrict__ emb,
                                                         const int* __restrict__ trip,
                                                         int rowsPerBlock, int T,
                                                         float* __restrict__ ws) {
    __shared__ __align__(16) char lds[2][128 * 128];
    __shared__ float csred[D];
    const int tid = threadIdx.x;

    if (blockIdx.x < GB) {
        const int l = tid & 63, w = tid >> 6, r0 = blockIdx.x * rowsPerBlock;
        const int rT = w & 3, c0 = (w >> 2) * 2;
        f32x16 acc0 = {}, acc1 = {};
        float cs[4] = {0.f, 0.f, 0.f, 0.f};
        const int d0 = (tid & 31) * 4;

        auto stage = [&](int cc, int b) {
#pragma unroll
            for (int j = 0; j < 2; ++j) {
                const int k = j * 32 + (tid >> 5) * 2;
                const float* base = emb + (size_t)(r0 + cc * 64 + k) * D + d0;
                float4 a = *(const float4*)base;
                float4 bv = *(const float4*)(base + D);
#pragma unroll
                for (int i = 0; i < 4; ++i) {
                    float av = ((const float*)&a)[i], bb = ((const float*)&bv)[i];
                    cs[i] += av + bb;
                    unsigned slotp = (unsigned)(k >> 3) ^ (unsigned)((tid & 31) & 7);
                    unsigned off = (unsigned)(d0 + i) * 128u + slotp * 16u + (unsigned)((k & 7) << 1);
                    *(unsigned*)(&lds[b][off]) = (unsigned)f2bf(av) | ((unsigned)f2bf(bb) << 16);
                }
            }
        };
        auto frag = [&](int t, int kb, int b) -> bf16x8 {
            const int d = t * 32 + (l & 31);
            const int k = kb + (l >> 5) * 8;
            unsigned slotp = (unsigned)(k >> 3) ^ ((unsigned)(d >> 2) & 7u);
            return *(const bf16x8*)(&lds[b][(unsigned)d * 128u + slotp * 16u]);
        };
        const int nChunks = rowsPerBlock / 64;
        stage(0, 0);
        for (int cc = 0; cc < nChunks; ++cc) {
            const int b = cc & 1;
            __syncthreads();
            if (cc + 1 < nChunks) stage(cc + 1, b ^ 1);
#pragma unroll
            for (int kb = 0; kb < 64; kb += 16) {
                bf16x8 fr = frag(rT, kb, b);
                bf16x8 f0 = frag(c0, kb, b);
                bf16x8 f1 = frag(c0 + 1, kb, b);
                acc0 = __builtin_amdgcn_mfma_f32_32x32x16_bf16(fr, f0, acc0, 0, 0, 0);
                acc1 = __builtin_amdgcn_mfma_f32_32x32x16_bf16(fr, f1, acc1, 0, 0, 0);
            }
        }
        __syncthreads();
        if (tid < D) csred[tid] = 0.f;
        __syncthreads();
#pragma unroll
        for (int i = 0; i < 4; ++i) atomicAdd(&csred[d0 + i], cs[i]);
        __syncthreads();
        if (tid < D) atomicAdd(&ws[WS_COLSUM + tid], csred[tid]);
        const int row_hi = (l >> 5) * 4, col = l & 31;
#pragma unroll
        for (int reg = 0; reg < 16; ++reg) {
            const int row32 = (reg & 3) + 8 * (reg >> 2) + row_hi;
            const int gr = (rT * 32 + row32) * D;
            atomicAdd(&ws[WS_GRAM + gr + c0 * 32 + col], acc0[reg]);
            atomicAdd(&ws[WS_GRAM + gr + (c0 + 1) * 32 + col], acc1[reg]);
        }
    } else {
        const int li = tid & 31, hwl = tid >> 5;
        const int hw = (blockIdx.x - GB) * 16 + hwl;
        const int NH = 1024 * 16;
        float wsum = 0.f;
        for (int t0 = hw; t0 < T; t0 += 4 * NH) {
            float4 P[4], Q[4], R[4];
#pragma unroll
            for (int k = 0; k < 4; ++k) {
                const int t = t0 + k * NH;
                if (t < T) {
                    const int i0 = trip[3 * t], i1 = trip[3 * t + 1], i2 = trip[3 * t + 2];
                    P[k] = ((const float4*)(emb + (size_t)i0 * D))[li];
                    Q[k] = ((const float4*)(emb + (size_t)i1 * D))[li];
                    R[k] = ((const float4*)(emb + (size_t)i2 * D))[li];
                }
            }
#pragma unroll
            for (int k = 0; k < 4; ++k) {
                const int t = t0 + k * NH;
                if (t < T) {
                    float s = d2diff(P[k], Q[k], R[k]);
#pragma unroll
                    for (int off = 16; off; off >>= 1) s += __shfl_xor(s, off, 64);
                    if (li == 0) wsum += fmaxf(s + MARGIN, 0.f);
                }
            }
        }
        if (li == 0) csred[hwl] = wsum;
        __syncthreads();
        if (tid == 0) {
            float b = 0.f;
#pragma unroll
            for (int i = 0; i < 16; ++i) b += csred[i];
            atomicAdd(&ws[WS_TSUM], b);
        }
    }
}

extern "C" void kernel_launch(void* const* d_in, const int* in_sizes, int n_in,
                              void* d_out, int out_size, void* d_ws, size_t ws_size,
                              hipStream_t stream) {
    const float* emb  = (const float*)d_in[0];
    const int*   trip = (const int*)d_in[1];
    float*       out  = (float*)d_out;
    float*       ws   = (float*)d_ws;

    const int N = in_sizes[0] / D;   // 262144
    const int T = in_sizes[1] / 3;   // 262144

    hipMemsetAsync(d_ws, 0, WS_ZERO * sizeof(float), stream);

    const size_t needB = (size_t)WS_TAB_F * 4 + (size_t)N * D * 2;   // partials + bf16 table

    if (ws_size >= needB) {
        unsigned short* tab = (unsigned short*)(ws + WS_TAB_F);
        convert_kernel<<<CVB, 512, 0, stream>>>(emb, N / CVB, ws, tab);
        gram_trip<<<G2 + TB, 512, 0, stream>>>(tab, trip, T, N / G2, ws);
        reduce_partials<<<256, 512, 0, stream>>>(ws);
    } else {
        fused_fallback<<<GB + 1024, 512, 0, stream>>>(emb, trip, N / GB, T, ws);
    }

    finalize_kernel<<<1, 256, 0, stream>>>(ws, out, N, T);
}